// Round 2
// baseline (117.121 us; speedup 1.0000x reference)
//
#include <hip/hip_runtime.h>

typedef float  f32x4  __attribute__((ext_vector_type(4)));
typedef float  f32x2  __attribute__((ext_vector_type(2)));
typedef short  bf16x8 __attribute__((ext_vector_type(8)));
typedef int    i32x4  __attribute__((ext_vector_type(4)));

#define NNODE 3072
#define DIN   128
#define DOUT  128
#define NREL  3
#define NH    4
#define HD    32
#define NC    144     // padded aggregation-column count (128 U + 4 V + 1 deg + 11 pad)
#define NTL   9       // 144/16 N-tiles

static __device__ __forceinline__ unsigned short f2bf(float v) {
  unsigned u = __builtin_bit_cast(unsigned, v);
  u += 0x7FFFu + ((u >> 16) & 1u);          // round-to-nearest-even
  return (unsigned short)(u >> 16);
}

// ---------------- K0: init out = bias (out is poisoned before timing) ----------------
__global__ __launch_bounds__(256, 1) void k0_init(
    const float* __restrict__ bias, float* __restrict__ out)
{
  const int tid = blockIdx.x * 256 + threadIdx.x;   // 0..98303 (3072*128/4)
  f32x4 b = *(const f32x4*)(bias + (tid & 31) * 4);
  *((f32x4*)out + tid) = b;
}

// ---------------- K1: t = F * W_r^T, attention scalars, build M^T (bf16) ----------------
// grid (48, 3), block 256. Each block: one relation, 64 rows.  (validated numerics)
__global__ __launch_bounds__(256, 1) void k1_prep(
    const float* __restrict__ feat, const float* __restrict__ W,
    const float* __restrict__ av, unsigned short* __restrict__ Mt,
    float* __restrict__ Es)
{
  const int jt = blockIdx.x;     // 0..47
  const int r  = blockIdx.y;     // 0..2
  const int t  = threadIdx.x;    // 0..255
  const int jb = jt * 64;

  __shared__ float Wl[128 * 130];   // W_r row-major, row stride 130
  __shared__ float Fl[64 * 129];    // feature tile, stride 129
  __shared__ float Tl[64 * 129];    // t tile, stride 129
  __shared__ float El[64 * 5];      // exp(s_dst)

  const float* Wr = W + r * DOUT * DIN;
  for (int idx = t * 4; idx < DOUT * DIN; idx += 1024) {
    float4 v = *(const float4*)(Wr + idx);
    int o = idx >> 7, k = idx & 127;
    float* d = Wl + o * 130 + k;
    d[0] = v.x; d[1] = v.y; d[2] = v.z; d[3] = v.w;
  }
  for (int idx = t * 4; idx < 64 * DIN; idx += 1024) {
    float4 v = *(const float4*)(feat + (size_t)jb * DIN + idx);
    int n = idx >> 7, k = idx & 127;
    float* d = Fl + n * 129 + k;
    d[0] = v.x; d[1] = v.y; d[2] = v.z; d[3] = v.w;
  }
  __syncthreads();

  {
    const int ng = t & 15, og = t >> 4;
    float acc[4][8] = {};
    for (int k = 0; k < DIN; k += 4) {
      float wv[4][8];
      #pragma unroll
      for (int oo = 0; oo < 8; ++oo) {
        const float* wr2 = Wl + (og * 8 + oo) * 130 + k;
        f32x2 a01 = *(const f32x2*)wr2;
        f32x2 a23 = *(const f32x2*)(wr2 + 2);
        wv[0][oo] = a01[0]; wv[1][oo] = a01[1];
        wv[2][oo] = a23[0]; wv[3][oo] = a23[1];
      }
      #pragma unroll
      for (int nn = 0; nn < 4; ++nn) {
        const float* fr = Fl + (ng * 4 + nn) * 129 + k;
        float f0 = fr[0], f1 = fr[1], f2 = fr[2], f3 = fr[3];
        #pragma unroll
        for (int oo = 0; oo < 8; ++oo) {
          float s = acc[nn][oo];
          s = fmaf(f0, wv[0][oo], s);
          s = fmaf(f1, wv[1][oo], s);
          s = fmaf(f2, wv[2][oo], s);
          s = fmaf(f3, wv[3][oo], s);
          acc[nn][oo] = s;
        }
      }
    }
    #pragma unroll
    for (int nn = 0; nn < 4; ++nn)
      #pragma unroll
      for (int oo = 0; oo < 8; ++oo)
        Tl[(ng * 4 + nn) * 129 + og * 8 + oo] = acc[nn][oo];
  }
  __syncthreads();

  {
    const int n = t & 63, h = t >> 6;
    const float* tr = Tl + n * 129 + h * HD;
    const float* as = av + r * 2 * HD;
    float ss = 0.f, sd = 0.f;
    #pragma unroll
    for (int d = 0; d < HD; ++d) {
      float tvv = tr[d];
      ss = fmaf(tvv, as[d],      ss);
      sd = fmaf(tvv, as[HD + d], sd);
    }
    Es[((size_t)r * NNODE + jb + n) * NH + h] = expf(ss);
    El[n * 5 + h] = expf(sd);
  }
  __syncthreads();

  {
    const int n = t & 63, cb = t >> 6;
    unsigned short* mtb = Mt + (size_t)r * NC * NNODE + jb + n;
    #pragma unroll
    for (int ci = 0; ci < 36; ++ci) {
      int c = cb * 36 + ci;
      float v;
      if (c < DOUT)            v = Tl[n * 129 + c] * El[n * 5 + (c >> 5)];
      else if (c < DOUT + NH)  v = El[n * 5 + (c - DOUT)];
      else if (c == DOUT + NH) v = 1.0f;
      else                     v = 0.0f;
      mtb[(size_t)c * NNODE] = f2bf(v);
    }
  }
}

// ---------------- K2: C = A (binary) @ M, fused finalize, atomicAdd into out ----------------
// grid (192, 3), block 256 = 4 waves. Block: 16 rows x 144 cols; waves split K (768 each).
// 576 blocks, ~140 VGPR -> all co-resident on 256 CUs (no tail quantization).
__global__ __launch_bounds__(256, 1) void k2_agg(
    const int* __restrict__ adj, const unsigned short* __restrict__ Mt,
    const float* __restrict__ Es, float* __restrict__ out)
{
  const int it = blockIdx.x;    // 0..191
  const int r  = blockIdx.y;    // 0..2
  const int t  = threadIdx.x;
  const int wv = t >> 6;        // wave -> K chunk
  const int l  = t & 63;
  const int l16 = l & 15, l4 = l >> 4;
  const int ib = it * 16;
  const int k0 = wv * 768;

  const int* arow = adj + (size_t)r * NNODE * NNODE + (size_t)(ib + l16) * NNODE + k0 + l4 * 8;
  const unsigned short* bptr = Mt + (size_t)r * NC * NNODE + (size_t)l16 * NNODE + k0 + l4 * 8;

  f32x4 acc[NTL] = {};

  i32x4  aA[2], aB[2];
  bf16x8 bA[NTL], bB[NTL];

  #define LOADF(AA, BB, ks) do {                                      \
    const int off_ = (ks) * 32;                                       \
    AA[0] = *(const i32x4*)(arow + off_);                             \
    AA[1] = *(const i32x4*)(arow + off_ + 4);                         \
    _Pragma("unroll")                                                 \
    for (int nt = 0; nt < NTL; ++nt)                                  \
      BB[nt] = *(const bf16x8*)(bptr + off_ + (size_t)nt * 16 * NNODE); \
  } while (0)

  #define CVT1(x) __builtin_bit_cast(bf16x8, (i32x4){                 \
      (x[0][0] | (x[0][1] << 16)) * 0x3F80, (x[0][2] | (x[0][3] << 16)) * 0x3F80, \
      (x[1][0] | (x[1][1] << 16)) * 0x3F80, (x[1][2] | (x[1][3] << 16)) * 0x3F80 })

  #define MFMAS(AA, BB) do {                                          \
    bf16x8 af = CVT1(AA);                                             \
    _Pragma("unroll")                                                 \
    for (int nt = 0; nt < NTL; ++nt)                                  \
      acc[nt] = __builtin_amdgcn_mfma_f32_16x16x32_bf16(af, BB[nt], acc[nt], 0, 0, 0); \
  } while (0)

  LOADF(aA, bA, 0);
  #pragma unroll 1
  for (int ks = 0; ks < 24; ks += 2) {
    if (ks + 1 < 24) LOADF(aB, bB, ks + 1);
    MFMAS(aA, bA);
    if (ks + 2 < 24) LOADF(aA, bA, ks + 2);
    MFMAS(aB, bB);
  }

  // intra-block K reduction in LDS (sequential waves, syncthreads-ordered)
  __shared__ float red[16 * 145];
  __shared__ float coefL[64];
  if (wv == 0) {
    #pragma unroll
    for (int nt = 0; nt < NTL; ++nt)
      #pragma unroll
      for (int rg = 0; rg < 4; ++rg)
        red[(l4 * 4 + rg) * 145 + nt * 16 + l16] = acc[nt][rg];
  }
  __syncthreads();
  #pragma unroll 1
  for (int w = 1; w < 4; ++w) {
    if (wv == w) {
      #pragma unroll
      for (int nt = 0; nt < NTL; ++nt)
        #pragma unroll
        for (int rg = 0; rg < 4; ++rg)
          red[(l4 * 4 + rg) * 145 + nt * 16 + l16] += acc[nt][rg];
    }
    __syncthreads();
  }

  // finalize: coef = e_src / (e_src*V + N - deg), folded 1/NREL
  if (t < 64) {
    int row = t >> 2, h = t & 3;
    float es = Es[((size_t)r * NNODE + ib + row) * NH + h];
    float V  = red[row * 145 + DOUT + h];
    float dg = red[row * 145 + DOUT + NH];
    coefL[row * 4 + h] = es / fmaf(es, V, (float)NNODE - dg) * (1.0f / NREL);
  }
  __syncthreads();

  #pragma unroll
  for (int idx = t; idx < 16 * DOUT; idx += 256) {
    int row = idx >> 7, c = idx & 127;
    atomicAdd(&out[(size_t)(ib + row) * DOUT + c],
              coefL[row * 4 + (c >> 5)] * red[row * 145 + c]);
  }
  #undef LOADF
  #undef CVT1
  #undef MFMAS
}

extern "C" void kernel_launch(void* const* d_in, const int* in_sizes, int n_in,
                              void* d_out, int out_size, void* d_ws, size_t ws_size,
                              hipStream_t stream) {
  const float* feat = (const float*)d_in[0];
  const int*   adj  = (const int*)d_in[1];
  const float* W    = (const float*)d_in[2];
  const float* av   = (const float*)d_in[3];
  const float* bias = (const float*)d_in[4];

  char* ws = (char*)d_ws;
  unsigned short* Mt = (unsigned short*)ws;                 // 3*144*3072*2  = 2,654,208 B
  float* Es = (float*)(ws + 2654208);                       // 3*3072*4*4    =   147,456 B
                                                            // total ws use: 2,801,664 B

  hipLaunchKernelGGL(k0_init, dim3(384), dim3(256), 0, stream, bias, (float*)d_out);
  hipLaunchKernelGGL(k1_prep, dim3(48, 3), dim3(256), 0, stream, feat, W, av, Mt, Es);
  hipLaunchKernelGGL(k2_agg,  dim3(192, 3), dim3(256), 0, stream, adj, Mt, Es, (float*)d_out);
}

// Round 3
// 63.583 us; speedup vs baseline: 1.8420x; 1.8420x over previous
//
#include <hip/hip_runtime.h>

typedef float  f32x4  __attribute__((ext_vector_type(4)));
typedef float  f32x2  __attribute__((ext_vector_type(2)));
typedef short  bf16x8 __attribute__((ext_vector_type(8)));
typedef int    i32x4  __attribute__((ext_vector_type(4)));

#define NNODE 3072
#define DIN   128
#define DOUT  128
#define NREL  3
#define NH    4
#define HD    32
#define NC    144     // aggregation columns: 128 U + 4 V + 1 deg + 11 pad
#define KCH   48      // K chunks of 64
#define CHB   9216    // ushorts per B chunk (9 tiles * 2 steps * 64 lanes * 8 = 18432 B)

static __device__ __forceinline__ unsigned short f2bf(float v) {
  unsigned u = __builtin_bit_cast(unsigned, v);
  u += 0x7FFFu + ((u >> 16) & 1u);          // round-to-nearest-even
  return (unsigned short)(u >> 16);
}

// ---------------- K0: init out = bias ----------------
__global__ __launch_bounds__(256, 1) void k0_init(
    const float* __restrict__ bias, float* __restrict__ out)
{
  const int tid = blockIdx.x * 256 + threadIdx.x;   // 3072*128/4 elems
  f32x4 b = *(const f32x4*)(bias + (tid & 31) * 4);
  *((f32x4*)out + tid) = b;
}

// ---------------- K1: t = F * W_r^T, attention scalars, build B in MFMA-fragment order ----
// grid (48, 3), block 256. Each block: one relation, 64 k-rows (= one 64-K chunk).
__global__ __launch_bounds__(256, 1) void k1_prep(
    const float* __restrict__ feat, const float* __restrict__ W,
    const float* __restrict__ av, unsigned short* __restrict__ Mt,
    float* __restrict__ Es)
{
  const int jt = blockIdx.x;     // 0..47  (= K chunk index)
  const int r  = blockIdx.y;     // 0..2
  const int t  = threadIdx.x;    // 0..255
  const int jb = jt * 64;

  __shared__ float Wl[128 * 130];
  __shared__ float Fl[64 * 129];
  __shared__ float Tl[64 * 129];
  __shared__ float El[64 * 5];

  const float* Wr = W + r * DOUT * DIN;
  for (int idx = t * 4; idx < DOUT * DIN; idx += 1024) {
    float4 v = *(const float4*)(Wr + idx);
    int o = idx >> 7, k = idx & 127;
    float* d = Wl + o * 130 + k;
    d[0] = v.x; d[1] = v.y; d[2] = v.z; d[3] = v.w;
  }
  for (int idx = t * 4; idx < 64 * DIN; idx += 1024) {
    float4 v = *(const float4*)(feat + (size_t)jb * DIN + idx);
    int n = idx >> 7, k = idx & 127;
    float* d = Fl + n * 129 + k;
    d[0] = v.x; d[1] = v.y; d[2] = v.z; d[3] = v.w;
  }
  __syncthreads();

  {
    const int ng = t & 15, og = t >> 4;
    float acc[4][8] = {};
    for (int k = 0; k < DIN; k += 4) {
      float wv[4][8];
      #pragma unroll
      for (int oo = 0; oo < 8; ++oo) {
        const float* wr2 = Wl + (og * 8 + oo) * 130 + k;
        f32x2 a01 = *(const f32x2*)wr2;
        f32x2 a23 = *(const f32x2*)(wr2 + 2);
        wv[0][oo] = a01[0]; wv[1][oo] = a01[1];
        wv[2][oo] = a23[0]; wv[3][oo] = a23[1];
      }
      #pragma unroll
      for (int nn = 0; nn < 4; ++nn) {
        const float* fr = Fl + (ng * 4 + nn) * 129 + k;
        float f0 = fr[0], f1 = fr[1], f2 = fr[2], f3 = fr[3];
        #pragma unroll
        for (int oo = 0; oo < 8; ++oo) {
          float s = acc[nn][oo];
          s = fmaf(f0, wv[0][oo], s);
          s = fmaf(f1, wv[1][oo], s);
          s = fmaf(f2, wv[2][oo], s);
          s = fmaf(f3, wv[3][oo], s);
          acc[nn][oo] = s;
        }
      }
    }
    #pragma unroll
    for (int nn = 0; nn < 4; ++nn)
      #pragma unroll
      for (int oo = 0; oo < 8; ++oo)
        Tl[(ng * 4 + nn) * 129 + og * 8 + oo] = acc[nn][oo];
  }
  __syncthreads();

  {
    const int n = t & 63, h = t >> 6;
    const float* tr = Tl + n * 129 + h * HD;
    const float* as = av + r * 2 * HD;
    float ss = 0.f, sd = 0.f;
    #pragma unroll
    for (int d = 0; d < HD; ++d) {
      float tvv = tr[d];
      ss = fmaf(tvv, as[d],      ss);
      sd = fmaf(tvv, as[HD + d], sd);
    }
    Es[((size_t)r * NNODE + jb + n) * NH + h] = expf(ss);
    El[n * 5 + h] = expf(sd);
  }
  __syncthreads();

  {
    // write B in fragment order: chunk = [tile nt][step s][lane = k8*16 + (c&15)][elem = j&7]
    const int n = t & 63, cb = t >> 6;   // j = jb + n
    unsigned short* base = Mt + ((size_t)r * KCH + jt) * CHB;
    const int s = n >> 5, k8 = (n >> 3) & 3, elem = n & 7;
    const int lanebase = k8 * 16;
    #pragma unroll
    for (int ci = 0; ci < 36; ++ci) {
      int c = cb * 36 + ci;
      float v;
      if (c < DOUT)            v = Tl[n * 129 + c] * El[n * 5 + (c >> 5)];
      else if (c < DOUT + NH)  v = El[n * 5 + (c - DOUT)];
      else if (c == DOUT + NH) v = 1.0f;
      else                     v = 0.0f;
      int nt = c >> 4;
      base[(nt * 2 + s) * 512 + (lanebase + (c & 15)) * 8 + elem] = f2bf(v);
    }
  }
}

// ---------------- K2: C = A @ M with LDS-staged A (global_load_lds) + burst B, fused finalize ----
// grid (192, 3), block 192 = 3 waves; wave w owns col-tiles {3w,3w+1,3w+2}; full K per block.
__global__ __launch_bounds__(192, 1) void k2_agg(
    const int* __restrict__ adj, const unsigned short* __restrict__ Mt,
    const float* __restrict__ Es, float* __restrict__ out)
{
  const int it = blockIdx.x;    // 0..191
  const int r  = blockIdx.y;    // 0..2
  const int t  = threadIdx.x;   // 0..191
  const int wv = t >> 6;        // 0..2
  const int l  = t & 63;
  const int l16 = l & 15, l4 = l >> 4;
  const int ib = it * 16;

  __shared__ __align__(16) int Ash[2][1024];   // [buf][row 16][64 ints], 16B-chunk XOR swizzle
  __shared__ float red[16 * 145];
  __shared__ float coefL[64];

  // ---- A staging maps (dest byte = t*16 [+3072]; src 16B-chunk = destchunk ^ (row&7)) ----
  const size_t adjBase = (size_t)r * NNODE * NNODE + (size_t)ib * NNODE;
  const int r0row = t >> 4,        r0c = (t & 15) ^ (r0row & 7);
  const int r1row = 12 + (t >> 4), r1c = (t & 15) ^ (r1row & 7);   // wave0 only

  #define STAGEA(buf, kc) do {                                                    \
    const int* s0_ = adj + adjBase + (size_t)r0row * NNODE + (kc) * 64 + r0c * 4; \
    __builtin_amdgcn_global_load_lds(                                             \
        (const __attribute__((address_space(1))) void*)s0_,                       \
        (__attribute__((address_space(3))) void*)&Ash[buf][wv * 256], 16, 0, 0);  \
    if (t < 64) {                                                                 \
      const int* s1_ = adj + adjBase + (size_t)r1row * NNODE + (kc) * 64 + r1c * 4; \
      __builtin_amdgcn_global_load_lds(                                           \
          (const __attribute__((address_space(1))) void*)s1_,                     \
          (__attribute__((address_space(3))) void*)&Ash[buf][768], 16, 0, 0);     \
    }                                                                             \
  } while (0)

  // ---- B burst loads: wave-contiguous 1KB per (tile,step), fragment-ready ----
  const unsigned short* mtc = Mt + (size_t)r * KCH * CHB + (size_t)wv * 6 * 512 + (size_t)l * 8;
  bf16x8 Ba[3][2], Bb[3][2];
  #define LOADB(B, kc) do {                                                       \
    const unsigned short* p_ = mtc + (size_t)(kc) * CHB;                          \
    _Pragma("unroll")                                                             \
    for (int i_ = 0; i_ < 3; ++i_) {                                              \
      B[i_][0] = *(const bf16x8*)(p_ + (i_ * 2 + 0) * 512);                       \
      B[i_][1] = *(const bf16x8*)(p_ + (i_ * 2 + 1) * 512);                       \
    }                                                                             \
  } while (0)

  f32x4 acc[3] = {};
  const int arow = l16 * 64, xm = (l & 7) << 2, koff = l4 * 8;

  #define COMPUTE(buf, B) do {                                                    \
    _Pragma("unroll")                                                             \
    for (int s_ = 0; s_ < 2; ++s_) {                                              \
      i32x4 a0 = *(const i32x4*)&Ash[buf][arow + ((s_ * 32 + koff + 0) ^ xm)];    \
      i32x4 a1 = *(const i32x4*)&Ash[buf][arow + ((s_ * 32 + koff + 4) ^ xm)];    \
      bf16x8 af = __builtin_bit_cast(bf16x8, (i32x4){                             \
        (a0[0] | (a0[1] << 16)) * 0x3F80, (a0[2] | (a0[3] << 16)) * 0x3F80,       \
        (a1[0] | (a1[1] << 16)) * 0x3F80, (a1[2] | (a1[3] << 16)) * 0x3F80 });    \
      _Pragma("unroll")                                                           \
      for (int i_ = 0; i_ < 3; ++i_)                                              \
        acc[i_] = __builtin_amdgcn_mfma_f32_16x16x32_bf16(af, B[i_][s_], acc[i_], 0, 0, 0); \
    }                                                                             \
  } while (0)

  STAGEA(0, 0); LOADB(Ba, 0);
  __syncthreads();
  #pragma unroll 1
  for (int kc = 0; kc < KCH; kc += 2) {
    STAGEA(1, kc + 1); LOADB(Bb, kc + 1);
    COMPUTE(0, Ba);
    __syncthreads();
    if (kc + 2 < KCH) { STAGEA(0, kc + 2); LOADB(Ba, kc + 2); }
    COMPUTE(1, Bb);
    __syncthreads();
  }

  // ---- partials to LDS (disjoint cols per wave), then fused finalize + atomic out ----
  #pragma unroll
  for (int i = 0; i < 3; ++i) {
    int nt = wv * 3 + i;
    #pragma unroll
    for (int rg = 0; rg < 4; ++rg)
      red[(l4 * 4 + rg) * 145 + nt * 16 + l16] = acc[i][rg];
  }
  __syncthreads();

  if (t < 64) {
    int row = t >> 2, h = t & 3;
    float es = Es[((size_t)r * NNODE + ib + row) * NH + h];
    float V  = red[row * 145 + DOUT + h];
    float dg = red[row * 145 + DOUT + NH];
    coefL[row * 4 + h] = es / fmaf(es, V, (float)NNODE - dg) * (1.0f / NREL);
  }
  __syncthreads();

  for (int idx = t; idx < 16 * DOUT; idx += 192) {
    int row = idx >> 7, c = idx & 127;
    atomicAdd(&out[(size_t)(ib + row) * DOUT + c],
              coefL[row * 4 + (c >> 5)] * red[row * 145 + c]);
  }
  #undef STAGEA
  #undef LOADB
  #undef COMPUTE
}

extern "C" void kernel_launch(void* const* d_in, const int* in_sizes, int n_in,
                              void* d_out, int out_size, void* d_ws, size_t ws_size,
                              hipStream_t stream) {
  const float* feat = (const float*)d_in[0];
  const int*   adj  = (const int*)d_in[1];
  const float* W    = (const float*)d_in[2];
  const float* av   = (const float*)d_in[3];
  const float* bias = (const float*)d_in[4];

  char* ws = (char*)d_ws;
  unsigned short* Mt = (unsigned short*)ws;                 // 3*48*9216*2  = 2,654,208 B
  float* Es = (float*)(ws + 2654208);                       // 3*3072*4*4   =   147,456 B
                                                            // total ws use: 2,801,664 B

  hipLaunchKernelGGL(k0_init, dim3(384), dim3(256), 0, stream, bias, (float*)d_out);
  hipLaunchKernelGGL(k1_prep, dim3(48, 3), dim3(256), 0, stream, feat, W, av, Mt, Es);
  hipLaunchKernelGGL(k2_agg,  dim3(192, 3), dim3(192), 0, stream, adj, Mt, Es, (float*)d_out);
}